// Round 10
// baseline (1015.567 us; speedup 1.0000x reference)
//
#include <hip/hip_runtime.h>
#include <hip/hip_bf16.h>

#define DIN 49
#define HIN 32
#define WIN 64
#define CIN 32
#define DOUT 193
#define HOUT 256
#define WOUT 512
#define NPIX (HOUT * WOUT)      // 131072
#define NUPS (DOUT * NPIX)      // 25296896
#define NCONV (DIN * HIN * WIN) // 100352
#define DSPLIT 64
#define NZ 4 // 3 full z-slices of 64 + 1-plane tail (d=192)
#define CGRP 8 // conv channel groups (4 ci each)

// LGA LDS geometry: d-contiguous per pixel, 97-word segment stride.
// Round-9 post-mortem: seg stride 96 words == 0 mod 32 banks put every
// staging ds_write_b32's 64 lanes on 8 banks (~4x tax, 1400 cyc/blk-chunk).
// 97 (odd) spreads seg across banks: writes become 2 lanes/bank (free).
#define ROWS 20      // h halo rows
#define PIXSTRIDE 12 // words per pixel (10 planes + 2 pad; 48 B, 16B-aligned)
#define SEGW 97      // words per 8-pixel segment (96 data + 1 pad)
#define ROWW 388     // words per staged row (4 segments)
#define SUWORDS 7760 // 20 rows

// ---------------------------------------------------------------------------
// Kernel 1: 3x3x3 conv, 32 -> 1 ch, zero pad 1, split 8 ways over channels.
// ---------------------------------------------------------------------------
__global__ void conv3d_kernel(const float* __restrict__ x,
                              const float* __restrict__ w,
                              float* __restrict__ partial) {
    __shared__ float ws[4 * 27];
    const int grp = blockIdx.y;
    for (int t = threadIdx.x; t < 4 * 27; t += blockDim.x)
        ws[t] = w[grp * (4 * 27) + t];
    __syncthreads();

    int idx = blockIdx.x * blockDim.x + threadIdx.x; // NCONV = 392*256 exact
    int wq = idx % WIN;
    int t2 = idx / WIN;
    int hq = t2 % HIN;
    int dq = t2 / HIN;

    float acc = 0.f;
    const float* xg = x + (size_t)grp * 4 * NCONV;
#pragma unroll
    for (int cl = 0; cl < 4; ++cl) {
        const float* xb = xg + cl * NCONV;
        const float* wb = ws + cl * 27;
#pragma unroll
        for (int kd = 0; kd < 3; ++kd) {
            int zd = dq + kd - 1;
            if (zd < 0 || zd >= DIN) continue;
#pragma unroll
            for (int kh = 0; kh < 3; ++kh) {
                int zh = hq + kh - 1;
                if (zh < 0 || zh >= HIN) continue;
#pragma unroll
                for (int kw = 0; kw < 3; ++kw) {
                    int zw = wq + kw - 1;
                    if (zw < 0 || zw >= WIN) continue;
                    acc += xb[(zd * HIN + zh) * WIN + zw] *
                           wb[(kd * 3 + kh) * 3 + kw];
                }
            }
        }
    }
    partial[(size_t)grp * NCONV + idx] = acc;
}

// ---------------------------------------------------------------------------
// Kernel 1b: fold 8 conv partials -> c.
// ---------------------------------------------------------------------------
__global__ void convfold_kernel(const float* __restrict__ partial,
                                float* __restrict__ c) {
    int idx = blockIdx.x * blockDim.x + threadIdx.x;
    float s = 0.f;
#pragma unroll
    for (int g = 0; g < CGRP; ++g) s += partial[(size_t)g * NCONV + idx];
    c[idx] = s;
}

// ---------------------------------------------------------------------------
// Kernel 2: trilinear upsample, 8 outputs/thread along w, uint4 stores.
// ---------------------------------------------------------------------------
__global__ void upsample_kernel(const float* __restrict__ c,
                                __hip_bfloat16* __restrict__ u) {
    int t = blockIdx.x * blockDim.x + threadIdx.x;
    int wc = t & 63;
    int rest = t >> 6;
    int hh = rest & 255;
    int dd = rest >> 8;
    if (dd >= DOUT) return;

    float fd = (dd + 0.5f) * (49.0f / 193.0f) - 0.5f;
    fd = fminf(fmaxf(fd, 0.f), (float)(DIN - 1));
    int d0 = min((int)fd, DIN - 2);
    float ad = fd - (float)d0;

    float fh = (hh + 0.5f) * 0.125f - 0.5f;
    fh = fminf(fmaxf(fh, 0.f), (float)(HIN - 1));
    int h0 = min((int)fh, HIN - 2);
    float ah = fh - (float)h0;

    int cm1 = max(wc - 1, 0);
    int cp1 = min(wc + 1, WIN - 1);
    const float* p00 = c + (d0 * HIN + h0) * WIN;
    const float* p01 = p00 + WIN;
    const float* p10 = p00 + HIN * WIN;
    const float* p11 = p10 + WIN;

    float a[3];
    {
        float q00, q01, q10, q11;
        q00 = p00[cm1]; q01 = p01[cm1]; q10 = p10[cm1]; q11 = p11[cm1];
        a[0] = (q00 + ah * (q01 - q00)) * (1.f - ad) +
               (q10 + ah * (q11 - q10)) * ad;
        q00 = p00[wc]; q01 = p01[wc]; q10 = p10[wc]; q11 = p11[wc];
        a[1] = (q00 + ah * (q01 - q00)) * (1.f - ad) +
               (q10 + ah * (q11 - q10)) * ad;
        q00 = p00[cp1]; q01 = p01[cp1]; q10 = p10[cp1]; q11 = p11[cp1];
        a[2] = (q00 + ah * (q01 - q00)) * (1.f - ad) +
               (q10 + ah * (q11 - q10)) * ad;
    }

    union {
        unsigned short us[8];
        uint4 v4;
    } pk;
#pragma unroll
    for (int i = 0; i < 8; ++i) {
        float fw = (float)(wc * 8 + i) * 0.125f + (0.0625f - 0.5f);
        fw = fminf(fmaxf(fw, 0.f), (float)(WIN - 1));
        int w0 = min((int)fw, WIN - 2);
        float aw = fw - (float)w0;
        int idx = w0 - (wc - 1);
        float lo = (idx == 0) ? a[0] : a[1];
        float hi = (idx == 0) ? a[1] : a[2];
        float v = lo + aw * (hi - lo);
        __hip_bfloat16 b = __float2bfloat16(v);
        unsigned short usv;
        __builtin_memcpy(&usv, &b, 2);
        pk.us[i] = usv;
    }
    *((uint4*)(u + (size_t)dd * NPIX + hh * WOUT + wc * 8)) = pk.v4;
}

// ---------------------------------------------------------------------------
// LGA: 16x16 pixel tile x DSPLIT d-planes per block. Single-buffer LDS
// (load -> barrier -> write -> barrier -> compute). d-contiguous layout with
// seg stride 97 (bank-conflict-free staging writes). Register budget tuned
// for VGPR <= 128 (4 waves/SIMD): lbase recomputed post-barrier, cb[5] col
// offsets hoisted. NO forced occupancy (rounds 4/6: forcing -> spill).
// MODE 0: write volume (bf16). MODE 1: per-z online softmin partials.
// ---------------------------------------------------------------------------
__device__ __forceinline__ unsigned short bf16bits(float f) {
    __hip_bfloat16 h = __float2bfloat16(f);
    unsigned short b;
    __builtin_memcpy(&b, &h, 2);
    return b;
}

template <int MODE>
__global__ __launch_bounds__(256) void lga_kernel(
    const __hip_bfloat16* __restrict__ xin,
    const float* __restrict__ lg1,
    __hip_bfloat16* __restrict__ yout,
    float* __restrict__ part) {
    const int tid = threadIdx.x;
    const int tx = tid & 15;
    const int ty = tid >> 4;
    const int w0p = blockIdx.x * 16;
    const int h0p = blockIdx.y * 16;
    const int zb = blockIdx.z * DSPLIT;
    const int dend = min(zb + DSPLIT, DOUT);
    const int pix = (h0p + ty) * WOUT + (w0p + tx);
    const unsigned short* xus = (const unsigned short*)xin;

    __shared__ __align__(16) float su[SUWORDS];

    // ---- guidance: single pass, un-normalized, bf16 pairs (38 regs) ----
    float asum = 0.f;
    unsigned gp[38];
#pragma unroll
    for (int p = 0; p < 38; ++p) {
        int c0 = 2 * p, c1 = 2 * p + 1;
        float w0 = lg1[c0 * NPIX + pix];
        float w1 = (c1 < 75) ? lg1[c1 * NPIX + pix] : 0.f;
        unsigned b0 = bf16bits(w0), b1 = bf16bits(w1);
        asum += fabsf(__uint_as_float(b0 << 16)) +
                fabsf(__uint_as_float(b1 << 16));
        gp[p] = b0 | (b1 << 16);
    }
    const float inv = 1.f / fmaxf(asum, 1e-12f);

// weight #idx (0..74), idx compile-time
#define GW(idx)                                              \
    __uint_as_float(((idx) & 1) ? (gp[(idx) >> 1] & 0xFFFF0000u) \
                                : (gp[(idx) >> 1] << 16))

    // Per-j column offsets in the seg-97 layout (col = tx+6+j, j=0..4).
    int cb[5];
#pragma unroll
    for (int j = 0; j < 5; ++j) {
        int cc = tx + 6 + j;
        cb[j] = ty * ROWW + (cc >> 3) * SEGW + (cc & 7) * PIXSTRIDE;
    }
    __hip_bfloat16* ybase = yout + pix;

    float m = -1e30f, l = 0.f, s_acc = 0.f; // MODE 1 online-softmin state

    for (int d0 = zb; d0 < dend; d0 += 8) {
        // ---- staging: decode jobs + issue loads (no lbase array) ----
        uint4 dat[4];
#pragma unroll
        for (int k = 0; k < 4; ++k) {
            const bool a = (k < 3) || (tid < 32); // NJOBS = 800
            int j = tid + k * 256;
            int seg = j & 3;
            int rowjob = j >> 2;
            int dl = rowjob / 20;
            int r = rowjob - dl * 20;
            int gh = h0p - 2 + r;
            int gwb = w0p - 8 + seg * 8;
            int gd = d0 - 1 + dl;
            uint4 v = make_uint4(0u, 0u, 0u, 0u);
            if (a && gd >= 0 && gd < DOUT && gh >= 0 && gh < HOUT &&
                gwb >= 0 && (gwb + 8) <= WOUT)
                v = *(const uint4*)(xus + (size_t)gd * NPIX + gh * WOUT + gwb);
            dat[k] = v;
        }
        __syncthreads(); // previous chunk's readers done
#pragma unroll
        for (int k = 0; k < 4; ++k) {
            if (k < 3 || tid < 32) {
                int j = tid + k * 256;
                int seg = j & 3;
                int rowjob = j >> 2;
                int dl = rowjob / 20;
                int r = rowjob - dl * 20;
                int base = r * ROWW + seg * SEGW + dl;
                unsigned q;
                q = dat[k].x;
                su[base + 0 * PIXSTRIDE] = __uint_as_float(q << 16);
                su[base + 1 * PIXSTRIDE] = __uint_as_float(q & 0xFFFF0000u);
                q = dat[k].y;
                su[base + 2 * PIXSTRIDE] = __uint_as_float(q << 16);
                su[base + 3 * PIXSTRIDE] = __uint_as_float(q & 0xFFFF0000u);
                q = dat[k].z;
                su[base + 4 * PIXSTRIDE] = __uint_as_float(q << 16);
                su[base + 5 * PIXSTRIDE] = __uint_as_float(q & 0xFFFF0000u);
                q = dat[k].w;
                su[base + 6 * PIXSTRIDE] = __uint_as_float(q << 16);
                su[base + 7 * PIXSTRIDE] = __uint_as_float(q & 0xFFFF0000u);
            }
        }
        __syncthreads();

        float acc[8] = {0.f, 0.f, 0.f, 0.f, 0.f, 0.f, 0.f, 0.f};
#pragma unroll
        for (int i = 0; i < 5; ++i) {
#pragma unroll
            for (int j = 0; j < 5; ++j) {
                const int t = i * 5 + j;
                const float* sp = su + cb[j] + i * ROWW;
                float4 va = *(const float4*)sp;
                float4 vb = *(const float4*)(sp + 4);
                float2 vc = *(const float2*)(sp + 8);
                const float g0 = GW(t);
                const float g1 = GW(25 + t);
                const float g2 = GW(50 + t);
                acc[0] += g1 * va.x + g0 * va.y + g2 * va.z;
                acc[1] += g1 * va.y + g0 * va.z + g2 * va.w;
                acc[2] += g1 * va.z + g0 * va.w + g2 * vb.x;
                acc[3] += g1 * va.w + g0 * vb.x + g2 * vb.y;
                acc[4] += g1 * vb.x + g0 * vb.y + g2 * vb.z;
                acc[5] += g1 * vb.y + g0 * vb.z + g2 * vb.w;
                acc[6] += g1 * vb.z + g0 * vb.w + g2 * vc.x;
                acc[7] += g1 * vb.w + g0 * vc.x + g2 * vc.y;
            }
        }

        if (MODE == 0) {
            if (d0 + 8 <= dend) {
#pragma unroll
                for (int dd = 0; dd < 8; ++dd)
                    ybase[(size_t)(d0 + dd) * NPIX] =
                        __float2bfloat16(acc[dd] * inv);
            } else {
#pragma unroll
                for (int dd = 0; dd < 8; ++dd)
                    if (d0 + dd < dend)
                        ybase[(size_t)(d0 + dd) * NPIX] =
                            __float2bfloat16(acc[dd] * inv);
            }
        } else {
            if (d0 + 8 <= dend) {
                float v0 = -acc[0] * inv, v1 = -acc[1] * inv;
                float v2 = -acc[2] * inv, v3 = -acc[3] * inv;
                float v4 = -acc[4] * inv, v5 = -acc[5] * inv;
                float v6 = -acc[6] * inv, v7 = -acc[7] * inv;
                float mx = fmaxf(fmaxf(fmaxf(v0, v1), fmaxf(v2, v3)),
                                 fmaxf(fmaxf(v4, v5), fmaxf(v6, v7)));
                mx = fmaxf(mx, m);
                float sc = __expf(m - mx);
                float e0 = __expf(v0 - mx), e1 = __expf(v1 - mx);
                float e2 = __expf(v2 - mx), e3 = __expf(v3 - mx);
                float e4 = __expf(v4 - mx), e5 = __expf(v5 - mx);
                float e6 = __expf(v6 - mx), e7 = __expf(v7 - mx);
                l = l * sc + ((e0 + e1) + (e2 + e3)) + ((e4 + e5) + (e6 + e7));
                float fd0 = (float)d0;
                s_acc = s_acc * sc + e0 * fd0 + e1 * (fd0 + 1.f) +
                        e2 * (fd0 + 2.f) + e3 * (fd0 + 3.f) + e4 * (fd0 + 4.f) +
                        e5 * (fd0 + 5.f) + e6 * (fd0 + 6.f) + e7 * (fd0 + 7.f);
                m = mx;
            } else {
#pragma unroll
                for (int dd = 0; dd < 8; ++dd) {
                    int d = d0 + dd;
                    if (d < dend) {
                        float v = -acc[dd] * inv;
                        float mx = fmaxf(m, v);
                        float sc = __expf(m - mx);
                        float e = __expf(v - mx);
                        l = l * sc + e;
                        s_acc = s_acc * sc + e * (float)d;
                        m = mx;
                    }
                }
            }
        }
    }
#undef GW

    if (MODE == 1) {
        float* pz = part + (size_t)blockIdx.z * 3 * NPIX;
        pz[pix] = m;
        pz[NPIX + pix] = l;
        pz[2 * NPIX + pix] = s_acc;
    }
}

// ---------------------------------------------------------------------------
// Kernel 4: merge NZ online-softmin partials per pixel -> disparity.
// ---------------------------------------------------------------------------
__global__ void reduce2_kernel(const float* __restrict__ part,
                               float* __restrict__ out) {
    int pix = blockIdx.x * blockDim.x + threadIdx.x;
    float M = -1e30f, L = 0.f, S = 0.f;
#pragma unroll
    for (int z = 0; z < NZ; ++z) {
        const float* pz = part + (size_t)z * 3 * NPIX;
        float m = pz[pix];
        float l = pz[NPIX + pix];
        float s = pz[2 * NPIX + pix];
        float mx = fmaxf(M, m);
        float a = __expf(M - mx);
        float b = __expf(m - mx);
        L = L * a + l * b;
        S = S * a + s * b;
        M = mx;
    }
    out[pix] = S / L;
}

// ---------------------------------------------------------------------------
extern "C" void kernel_launch(void* const* d_in, const int* in_sizes, int n_in,
                              void* d_out, int out_size, void* d_ws,
                              size_t ws_size, hipStream_t stream) {
    const float* x = (const float*)d_in[0];
    const float* lg1 = (const float*)d_in[1];
    const float* cw = (const float*)d_in[2];
    float* out = (float*)d_out;

    // ws: c fp32 [100352] | u bf16 [NUPS] | y1 bf16 [NUPS].
    // conv partials [8][NCONV] overlay y1 (dead until LGA1, after fold).
    // LGA2's (m,l,s) partials overlay u (dead after LGA1).
    float* c = (float*)d_ws;
    __hip_bfloat16* u = (__hip_bfloat16*)((char*)d_ws + (size_t)NCONV * 4);
    __hip_bfloat16* y1 = u + (size_t)NUPS;
    float* cpart = (float*)y1;
    float* part = (float*)u;

    dim3 cgrid(NCONV / 256, CGRP);
    conv3d_kernel<<<cgrid, 256, 0, stream>>>(x, cw, cpart);
    convfold_kernel<<<NCONV / 256, 256, 0, stream>>>(cpart, c);
    upsample_kernel<<<(DOUT * HOUT * 64 + 255) / 256, 256, 0, stream>>>(c, u);

    dim3 grid(WOUT / 16, HOUT / 16, NZ); // 32 x 16 x 4 = 2048 blocks
    lga_kernel<0><<<grid, 256, 0, stream>>>(u, lg1, y1, nullptr);
    lga_kernel<1><<<grid, 256, 0, stream>>>(y1, lg1, nullptr, part);

    reduce2_kernel<<<NPIX / 256, 256, 0, stream>>>(part, out);
}

// Round 11
// 483.379 us; speedup vs baseline: 2.1010x; 2.1010x over previous
//
#include <hip/hip_runtime.h>
#include <hip/hip_bf16.h>

#define DIN 49
#define HIN 32
#define WIN 64
#define CIN 32
#define DOUT 193
#define HOUT 256
#define WOUT 512
#define NPIX (HOUT * WOUT)      // 131072
#define NUPS (DOUT * NPIX)      // 25296896
#define NCONV (DIN * HIN * WIN) // 100352
#define DSPLIT 64
#define NZ 4 // 3 full z-slices of 64 + 1-plane tail (d=192)
#define CGRP 8 // conv channel groups (4 ci each)

// LGA LDS geometry: d-contiguous per pixel (round-8 measured layout; the
// round-10 odd-stride "fix" broke float4 alignment -> 3x regression. The
// 8-way staging-write aliasing (~10% LDS tax) is structural and accepted).
#define ROWS 20      // h halo rows
#define ROWSTRIDE 33 // pixel-row stride in pixels
#define PIXSTRIDE 12 // words per pixel (10 planes + 2 pad; 48 B, 16B-aligned)
#define SUWORDS 7920

// ---------------------------------------------------------------------------
// Kernel 1: 3x3x3 conv, 32 -> 1 ch, zero pad 1, split 8 ways over channels.
// ---------------------------------------------------------------------------
__global__ void conv3d_kernel(const float* __restrict__ x,
                              const float* __restrict__ w,
                              float* __restrict__ partial) {
    __shared__ float ws[4 * 27];
    const int grp = blockIdx.y;
    for (int t = threadIdx.x; t < 4 * 27; t += blockDim.x)
        ws[t] = w[grp * (4 * 27) + t];
    __syncthreads();

    int idx = blockIdx.x * blockDim.x + threadIdx.x; // NCONV = 392*256 exact
    int wq = idx % WIN;
    int t2 = idx / WIN;
    int hq = t2 % HIN;
    int dq = t2 / HIN;

    float acc = 0.f;
    const float* xg = x + (size_t)grp * 4 * NCONV;
#pragma unroll
    for (int cl = 0; cl < 4; ++cl) {
        const float* xb = xg + cl * NCONV;
        const float* wb = ws + cl * 27;
#pragma unroll
        for (int kd = 0; kd < 3; ++kd) {
            int zd = dq + kd - 1;
            if (zd < 0 || zd >= DIN) continue;
#pragma unroll
            for (int kh = 0; kh < 3; ++kh) {
                int zh = hq + kh - 1;
                if (zh < 0 || zh >= HIN) continue;
#pragma unroll
                for (int kw = 0; kw < 3; ++kw) {
                    int zw = wq + kw - 1;
                    if (zw < 0 || zw >= WIN) continue;
                    acc += xb[(zd * HIN + zh) * WIN + zw] *
                           wb[(kd * 3 + kh) * 3 + kw];
                }
            }
        }
    }
    partial[(size_t)grp * NCONV + idx] = acc;
}

// ---------------------------------------------------------------------------
// Kernel 1b: fold 8 conv partials -> c.
// ---------------------------------------------------------------------------
__global__ void convfold_kernel(const float* __restrict__ partial,
                                float* __restrict__ c) {
    int idx = blockIdx.x * blockDim.x + threadIdx.x;
    float s = 0.f;
#pragma unroll
    for (int g = 0; g < CGRP; ++g) s += partial[(size_t)g * NCONV + idx];
    c[idx] = s;
}

// ---------------------------------------------------------------------------
// LGA: 16x16 pixel tile x DSPLIT d-planes per block. Single-buffer LDS
// (load -> barrier -> write -> barrier -> compute), round-8 measured layout.
// MODE 0 (pass 1): staging COMPUTES the trilinear upsample from c (392 KB,
//   L1/L2-resident) instead of loading u from HBM — removes the ~900-cyc
//   exposed HBM latency per chunk AND the separate upsample kernel.
// MODE 1 (pass 2): stages y1 (bf16) from HBM; fused online softmin.
// NO forced occupancy (rounds 4/6: forcing -> spill -> GBs of scratch).
// ---------------------------------------------------------------------------
__device__ __forceinline__ unsigned short bf16bits(float f) {
    __hip_bfloat16 h = __float2bfloat16(f);
    unsigned short b;
    __builtin_memcpy(&b, &h, 2);
    return b;
}

template <int MODE>
__global__ __launch_bounds__(256) void lga_kernel(
    const __hip_bfloat16* __restrict__ xin, // MODE 1 input volume
    const float* __restrict__ cvol,         // MODE 0 input (conv output)
    const float* __restrict__ lg1,
    __hip_bfloat16* __restrict__ yout,
    float* __restrict__ part) {
    const int tid = threadIdx.x;
    const int tx = tid & 15;
    const int ty = tid >> 4;
    const int w0p = blockIdx.x * 16;
    const int h0p = blockIdx.y * 16;
    const int zb = blockIdx.z * DSPLIT;
    const int dend = min(zb + DSPLIT, DOUT);
    const int pix = (h0p + ty) * WOUT + (w0p + tx);
    const unsigned short* xus = (const unsigned short*)xin;

    __shared__ __align__(16) float su[SUWORDS];

    // ---- guidance: single pass, un-normalized, bf16 pairs (38 regs) ----
    float asum = 0.f;
    unsigned gp[38];
#pragma unroll
    for (int p = 0; p < 38; ++p) {
        int c0 = 2 * p, c1 = 2 * p + 1;
        float w0 = lg1[c0 * NPIX + pix];
        float w1 = (c1 < 75) ? lg1[c1 * NPIX + pix] : 0.f;
        unsigned b0 = bf16bits(w0), b1 = bf16bits(w1);
        asum += fabsf(__uint_as_float(b0 << 16)) +
                fabsf(__uint_as_float(b1 << 16));
        gp[p] = b0 | (b1 << 16);
    }
    const float inv = 1.f / fmaxf(asum, 1e-12f);

// weight #idx (0..74), idx compile-time
#define GW(idx)                                              \
    __uint_as_float(((idx) & 1) ? (gp[(idx) >> 1] & 0xFFFF0000u) \
                                : (gp[(idx) >> 1] << 16))

    const int pbase = (ty * ROWSTRIDE + tx + 6) * PIXSTRIDE;
    __hip_bfloat16* ybase = yout + pix;

    float m = -1e30f, l = 0.f, s_acc = 0.f; // MODE 1 online-softmin state

    for (int d0 = zb; d0 < dend; d0 += 8) {
        // ==== staging phase ====
        if (MODE == 0) {
            // Trilerp from cvol. Phase A (pre-barrier): 12 L2-hot loads per
            // job, collapse d/h lerps into a[k][0..2]. Phase B (post-barrier):
            // w-lerp 8 cols and scatter-write d-contiguous LDS.
            float aq[4][3];
#pragma unroll
            for (int k = 0; k < 4; ++k) {
                const bool a = (k < 3) || (tid < 32); // NJOBS = 800
                int j = tid + k * 256;
                int seg = j & 3;
                int rowjob = j >> 2;
                int dl = rowjob / 20;
                int r = rowjob - dl * 20;
                int gh = h0p - 2 + r;
                int gwb = w0p - 8 + seg * 8;
                int gd = d0 - 1 + dl;
                if (a && gd >= 0 && gd < DOUT && gh >= 0 && gh < HOUT &&
                    gwb >= 0 && (gwb + 8) <= WOUT) {
                    float fd = (gd + 0.5f) * (49.0f / 193.0f) - 0.5f;
                    fd = fminf(fmaxf(fd, 0.f), (float)(DIN - 1));
                    int d0c = min((int)fd, DIN - 2);
                    float ad = fd - (float)d0c;
                    float fh = (gh + 0.5f) * 0.125f - 0.5f;
                    fh = fminf(fmaxf(fh, 0.f), (float)(HIN - 1));
                    int h0c = min((int)fh, HIN - 2);
                    float ah = fh - (float)h0c;
                    int g = gwb >> 3;
                    int cm1 = max(g - 1, 0);
                    int cp1 = min(g + 1, WIN - 1);
                    const float* p00 = cvol + (d0c * HIN + h0c) * WIN;
                    const float* p01 = p00 + WIN;
                    const float* p10 = p00 + HIN * WIN;
                    const float* p11 = p10 + WIN;
                    float q00, q01, q10, q11;
                    q00 = p00[cm1]; q01 = p01[cm1];
                    q10 = p10[cm1]; q11 = p11[cm1];
                    aq[k][0] = (q00 + ah * (q01 - q00)) * (1.f - ad) +
                               (q10 + ah * (q11 - q10)) * ad;
                    q00 = p00[g]; q01 = p01[g];
                    q10 = p10[g]; q11 = p11[g];
                    aq[k][1] = (q00 + ah * (q01 - q00)) * (1.f - ad) +
                               (q10 + ah * (q11 - q10)) * ad;
                    q00 = p00[cp1]; q01 = p01[cp1];
                    q10 = p10[cp1]; q11 = p11[cp1];
                    aq[k][2] = (q00 + ah * (q01 - q00)) * (1.f - ad) +
                               (q10 + ah * (q11 - q10)) * ad;
                } else {
                    aq[k][0] = aq[k][1] = aq[k][2] = 0.f;
                }
            }
            __syncthreads(); // previous chunk's readers done
#pragma unroll
            for (int k = 0; k < 4; ++k) {
                if (k < 3 || tid < 32) {
                    int j = tid + k * 256;
                    int seg = j & 3;
                    int rowjob = j >> 2;
                    int dl = rowjob / 20;
                    int r = rowjob - dl * 20;
                    int gwb = w0p - 8 + seg * 8;
                    int gd = d0 - 1 + dl;
                    int gh = h0p - 2 + r;
                    int base = (r * ROWSTRIDE + seg * 8) * PIXSTRIDE + dl;
                    bool inb = gd >= 0 && gd < DOUT && gh >= 0 && gh < HOUT &&
                               gwb >= 0 && (gwb + 8) <= WOUT;
                    int g = gwb >> 3;
#pragma unroll
                    for (int i = 0; i < 8; ++i) {
                        float v = 0.f;
                        if (inb) {
                            float fw =
                                (float)(gwb + i) * 0.125f + (0.0625f - 0.5f);
                            fw = fminf(fmaxf(fw, 0.f), (float)(WIN - 1));
                            int w0 = min((int)fw, WIN - 2);
                            float aw = fw - (float)w0;
                            int idx = w0 - (g - 1); // 0 or 1
                            float lo = (idx == 0) ? aq[k][0] : aq[k][1];
                            float hi = (idx == 0) ? aq[k][1] : aq[k][2];
                            v = lo + aw * (hi - lo);
                        }
                        su[base + i * PIXSTRIDE] = v;
                    }
                }
            }
        } else {
            // bf16 volume staging (round-8 measured path).
            uint4 dat[4];
            int lbase[4];
#pragma unroll
            for (int k = 0; k < 4; ++k) {
                const bool a = (k < 3) || (tid < 32); // NJOBS = 800
                int j = tid + k * 256;
                int seg = j & 3;
                int rowjob = j >> 2;
                int dl = rowjob / 20;
                int r = rowjob - dl * 20;
                int gh = h0p - 2 + r;
                int gwb = w0p - 8 + seg * 8;
                int gd = d0 - 1 + dl;
                lbase[k] = (r * ROWSTRIDE + seg * 8) * PIXSTRIDE + dl;
                uint4 v = make_uint4(0u, 0u, 0u, 0u);
                if (a && gd >= 0 && gd < DOUT && gh >= 0 && gh < HOUT &&
                    gwb >= 0 && (gwb + 8) <= WOUT)
                    v = *(const uint4*)(xus + (size_t)gd * NPIX + gh * WOUT +
                                        gwb);
                dat[k] = v;
            }
            __syncthreads(); // previous chunk's readers done
#pragma unroll
            for (int k = 0; k < 4; ++k) {
                if (k < 3 || tid < 32) {
                    int base = lbase[k];
                    unsigned q;
                    q = dat[k].x;
                    su[base + 0 * PIXSTRIDE] = __uint_as_float(q << 16);
                    su[base + 1 * PIXSTRIDE] = __uint_as_float(q & 0xFFFF0000u);
                    q = dat[k].y;
                    su[base + 2 * PIXSTRIDE] = __uint_as_float(q << 16);
                    su[base + 3 * PIXSTRIDE] = __uint_as_float(q & 0xFFFF0000u);
                    q = dat[k].z;
                    su[base + 4 * PIXSTRIDE] = __uint_as_float(q << 16);
                    su[base + 5 * PIXSTRIDE] = __uint_as_float(q & 0xFFFF0000u);
                    q = dat[k].w;
                    su[base + 6 * PIXSTRIDE] = __uint_as_float(q << 16);
                    su[base + 7 * PIXSTRIDE] = __uint_as_float(q & 0xFFFF0000u);
                }
            }
        }
        __syncthreads();

        // ==== compute phase (identical to round-8 measured kernel) ====
        float acc[8] = {0.f, 0.f, 0.f, 0.f, 0.f, 0.f, 0.f, 0.f};
#pragma unroll
        for (int i = 0; i < 5; ++i) {
#pragma unroll
            for (int j = 0; j < 5; ++j) {
                const int t = i * 5 + j;
                const float* sp = su + pbase + (i * ROWSTRIDE + j) * PIXSTRIDE;
                float4 va = *(const float4*)sp;
                float4 vb = *(const float4*)(sp + 4);
                float2 vc = *(const float2*)(sp + 8);
                const float g0 = GW(t);
                const float g1 = GW(25 + t);
                const float g2 = GW(50 + t);
                acc[0] += g1 * va.x + g0 * va.y + g2 * va.z;
                acc[1] += g1 * va.y + g0 * va.z + g2 * va.w;
                acc[2] += g1 * va.z + g0 * va.w + g2 * vb.x;
                acc[3] += g1 * va.w + g0 * vb.x + g2 * vb.y;
                acc[4] += g1 * vb.x + g0 * vb.y + g2 * vb.z;
                acc[5] += g1 * vb.y + g0 * vb.z + g2 * vb.w;
                acc[6] += g1 * vb.z + g0 * vb.w + g2 * vc.x;
                acc[7] += g1 * vb.w + g0 * vc.x + g2 * vc.y;
            }
        }

        if (MODE == 0) {
            if (d0 + 8 <= dend) {
#pragma unroll
                for (int dd = 0; dd < 8; ++dd)
                    ybase[(size_t)(d0 + dd) * NPIX] =
                        __float2bfloat16(acc[dd] * inv);
            } else {
#pragma unroll
                for (int dd = 0; dd < 8; ++dd)
                    if (d0 + dd < dend)
                        ybase[(size_t)(d0 + dd) * NPIX] =
                            __float2bfloat16(acc[dd] * inv);
            }
        } else {
            if (d0 + 8 <= dend) {
                float v0 = -acc[0] * inv, v1 = -acc[1] * inv;
                float v2 = -acc[2] * inv, v3 = -acc[3] * inv;
                float v4 = -acc[4] * inv, v5 = -acc[5] * inv;
                float v6 = -acc[6] * inv, v7 = -acc[7] * inv;
                float mx = fmaxf(fmaxf(fmaxf(v0, v1), fmaxf(v2, v3)),
                                 fmaxf(fmaxf(v4, v5), fmaxf(v6, v7)));
                mx = fmaxf(mx, m);
                float sc = __expf(m - mx);
                float e0 = __expf(v0 - mx), e1 = __expf(v1 - mx);
                float e2 = __expf(v2 - mx), e3 = __expf(v3 - mx);
                float e4 = __expf(v4 - mx), e5 = __expf(v5 - mx);
                float e6 = __expf(v6 - mx), e7 = __expf(v7 - mx);
                l = l * sc + ((e0 + e1) + (e2 + e3)) + ((e4 + e5) + (e6 + e7));
                float fd0 = (float)d0;
                s_acc = s_acc * sc + e0 * fd0 + e1 * (fd0 + 1.f) +
                        e2 * (fd0 + 2.f) + e3 * (fd0 + 3.f) + e4 * (fd0 + 4.f) +
                        e5 * (fd0 + 5.f) + e6 * (fd0 + 6.f) + e7 * (fd0 + 7.f);
                m = mx;
            } else {
#pragma unroll
                for (int dd = 0; dd < 8; ++dd) {
                    int d = d0 + dd;
                    if (d < dend) {
                        float v = -acc[dd] * inv;
                        float mx = fmaxf(m, v);
                        float sc = __expf(m - mx);
                        float e = __expf(v - mx);
                        l = l * sc + e;
                        s_acc = s_acc * sc + e * (float)d;
                        m = mx;
                    }
                }
            }
        }
    }
#undef GW

    if (MODE == 1) {
        float* pz = part + (size_t)blockIdx.z * 3 * NPIX;
        pz[pix] = m;
        pz[NPIX + pix] = l;
        pz[2 * NPIX + pix] = s_acc;
    }
}

// ---------------------------------------------------------------------------
// Kernel 4: merge NZ online-softmin partials per pixel -> disparity.
// ---------------------------------------------------------------------------
__global__ void reduce2_kernel(const float* __restrict__ part,
                               float* __restrict__ out) {
    int pix = blockIdx.x * blockDim.x + threadIdx.x;
    float M = -1e30f, L = 0.f, S = 0.f;
#pragma unroll
    for (int z = 0; z < NZ; ++z) {
        const float* pz = part + (size_t)z * 3 * NPIX;
        float m = pz[pix];
        float l = pz[NPIX + pix];
        float s = pz[2 * NPIX + pix];
        float mx = fmaxf(M, m);
        float a = __expf(M - mx);
        float b = __expf(m - mx);
        L = L * a + l * b;
        S = S * a + s * b;
        M = mx;
    }
    out[pix] = S / L;
}

// ---------------------------------------------------------------------------
extern "C" void kernel_launch(void* const* d_in, const int* in_sizes, int n_in,
                              void* d_out, int out_size, void* d_ws,
                              size_t ws_size, hipStream_t stream) {
    const float* x = (const float*)d_in[0];
    const float* lg1 = (const float*)d_in[1];
    const float* cw = (const float*)d_in[2];
    float* out = (float*)d_out;

    // ws: c fp32 [100352] | region A bf16 [NUPS] | region B bf16 [NUPS].
    // conv partials [8][NCONV] overlay region B (dead until LGA1 output).
    // LGA1 (fused upsample) writes y1 into region B; LGA2 reads y1, writes
    // (m,l,s) partials into region A.
    float* c = (float*)d_ws;
    __hip_bfloat16* regA = (__hip_bfloat16*)((char*)d_ws + (size_t)NCONV * 4);
    __hip_bfloat16* y1 = regA + (size_t)NUPS;
    float* cpart = (float*)y1;
    float* part = (float*)regA;

    dim3 cgrid(NCONV / 256, CGRP);
    conv3d_kernel<<<cgrid, 256, 0, stream>>>(x, cw, cpart);
    convfold_kernel<<<NCONV / 256, 256, 0, stream>>>(cpart, c);

    dim3 grid(WOUT / 16, HOUT / 16, NZ); // 32 x 16 x 4 = 2048 blocks
    lga_kernel<0><<<grid, 256, 0, stream>>>(nullptr, c, lg1, y1, nullptr);
    lga_kernel<1><<<grid, 256, 0, stream>>>(y1, nullptr, lg1, nullptr, part);

    reduce2_kernel<<<NPIX / 256, 256, 0, stream>>>(part, out);
}

// Round 12
// 397.332 us; speedup vs baseline: 2.5560x; 1.2166x over previous
//
#include <hip/hip_runtime.h>
#include <hip/hip_bf16.h>

#define DIN 49
#define HIN 32
#define WIN 64
#define CIN 32
#define DOUT 193
#define HOUT 256
#define WOUT 512
#define NPIX (HOUT * WOUT)      // 131072
#define NUPS (DOUT * NPIX)      // 25296896
#define NCONV (DIN * HIN * WIN) // 100352
#define DSPLIT 64
#define NZ 4 // 3 full z-slices of 64 + 1-plane tail (d=192)
#define CGRP 8 // conv channel groups (4 ci each)

// LGA LDS geometry: d-contiguous per pixel (round-8 measured layout).
#define ROWS 20      // h halo rows
#define ROWSTRIDE 33 // pixel-row stride in pixels
#define PIXSTRIDE 12 // words per pixel (10 planes + 2 pad; 48 B, 16B-aligned)
#define SUWORDS 7920

// ---------------------------------------------------------------------------
// Kernel 1: 3x3x3 conv, 32 -> 1 ch, zero pad 1, split 8 ways over channels.
// ---------------------------------------------------------------------------
__global__ void conv3d_kernel(const float* __restrict__ x,
                              const float* __restrict__ w,
                              float* __restrict__ partial) {
    __shared__ float ws[4 * 27];
    const int grp = blockIdx.y;
    for (int t = threadIdx.x; t < 4 * 27; t += blockDim.x)
        ws[t] = w[grp * (4 * 27) + t];
    __syncthreads();

    int idx = blockIdx.x * blockDim.x + threadIdx.x; // NCONV = 392*256 exact
    int wq = idx % WIN;
    int t2 = idx / WIN;
    int hq = t2 % HIN;
    int dq = t2 / HIN;

    float acc = 0.f;
    const float* xg = x + (size_t)grp * 4 * NCONV;
#pragma unroll
    for (int cl = 0; cl < 4; ++cl) {
        const float* xb = xg + cl * NCONV;
        const float* wb = ws + cl * 27;
#pragma unroll
        for (int kd = 0; kd < 3; ++kd) {
            int zd = dq + kd - 1;
            if (zd < 0 || zd >= DIN) continue;
#pragma unroll
            for (int kh = 0; kh < 3; ++kh) {
                int zh = hq + kh - 1;
                if (zh < 0 || zh >= HIN) continue;
#pragma unroll
                for (int kw = 0; kw < 3; ++kw) {
                    int zw = wq + kw - 1;
                    if (zw < 0 || zw >= WIN) continue;
                    acc += xb[(zd * HIN + zh) * WIN + zw] *
                           wb[(kd * 3 + kh) * 3 + kw];
                }
            }
        }
    }
    partial[(size_t)grp * NCONV + idx] = acc;
}

// ---------------------------------------------------------------------------
// Kernel 1b: fold 8 conv partials -> c.
// ---------------------------------------------------------------------------
__global__ void convfold_kernel(const float* __restrict__ partial,
                                float* __restrict__ c) {
    int idx = blockIdx.x * blockDim.x + threadIdx.x;
    float s = 0.f;
#pragma unroll
    for (int g = 0; g < CGRP; ++g) s += partial[(size_t)g * NCONV + idx];
    c[idx] = s;
}

__device__ __forceinline__ unsigned short bf16bits(float f) {
    __hip_bfloat16 h = __float2bfloat16(f);
    unsigned short b;
    __builtin_memcpy(&b, &h, 2);
    return b;
}

// weight #idx (0..74), idx compile-time
#define GW(idx)                                                  \
    __uint_as_float(((idx) & 1) ? (gp[(idx) >> 1] & 0xFFFF0000u) \
                                : (gp[(idx) >> 1] << 16))

// ---------------------------------------------------------------------------
// LGA pass 1: staging COMPUTES the trilinear upsample from c (L1/L2-hot,
// 392 KB) — no u volume in HBM, no separate upsample kernel. gwb is 8-aligned
// so the w-lerp weights are COMPILE-TIME constants; edge clamps collapse
// automatically because clamped neighbor columns give aq0==aq1 / aq2==aq1.
// aq packed bf16 (8 regs) to stay under the 128-VGPR occupancy cliff
// (m69: waves/SIMD halve at 64/128/256 — there is no 3-wave class).
// ---------------------------------------------------------------------------
__global__ __launch_bounds__(256) void lga1_kernel(
    const float* __restrict__ cvol,
    const float* __restrict__ lg1,
    __hip_bfloat16* __restrict__ yout) {
    const int tid = threadIdx.x;
    const int tx = tid & 15;
    const int ty = tid >> 4;
    const int w0p = blockIdx.x * 16;
    const int h0p = blockIdx.y * 16;
    const int zb = blockIdx.z * DSPLIT;
    const int dend = min(zb + DSPLIT, DOUT);
    const int pix = (h0p + ty) * WOUT + (w0p + tx);

    __shared__ __align__(16) float su[SUWORDS];

    // ---- guidance: single pass, un-normalized, bf16 pairs (38 regs) ----
    float asum = 0.f;
    unsigned gp[38];
#pragma unroll
    for (int p = 0; p < 38; ++p) {
        int c0 = 2 * p, c1 = 2 * p + 1;
        float w0 = lg1[c0 * NPIX + pix];
        float w1 = (c1 < 75) ? lg1[c1 * NPIX + pix] : 0.f;
        unsigned b0 = bf16bits(w0), b1 = bf16bits(w1);
        asum += fabsf(__uint_as_float(b0 << 16)) +
                fabsf(__uint_as_float(b1 << 16));
        gp[p] = b0 | (b1 << 16);
    }
    const float inv = 1.f / fmaxf(asum, 1e-12f);

    const int pbase = (ty * ROWSTRIDE + tx + 6) * PIXSTRIDE;
    __hip_bfloat16* ybase = yout + pix;

    for (int d0 = zb; d0 < dend; d0 += 8) {
        // ---- staging phase A (pre-barrier): d/h-lerp 3 cols per job ----
        unsigned aqp[4][2]; // 3 bf16 per job, packed
#pragma unroll
        for (int k = 0; k < 4; ++k) {
            const bool a = (k < 3) || (tid < 32); // NJOBS = 800
            int j = tid + k * 256;
            int seg = j & 3;
            int rowjob = j >> 2;
            int dl = rowjob / 20;
            int r = rowjob - dl * 20;
            int gh = h0p - 2 + r;
            int gwb = w0p - 8 + seg * 8;
            int gd = d0 - 1 + dl;
            if (a && gd >= 0 && gd < DOUT && gh >= 0 && gh < HOUT &&
                gwb >= 0 && (gwb + 8) <= WOUT) {
                float fd = (gd + 0.5f) * (49.0f / 193.0f) - 0.5f;
                fd = fminf(fmaxf(fd, 0.f), (float)(DIN - 1));
                int d0c = min((int)fd, DIN - 2);
                float ad = fd - (float)d0c;
                float fh = (gh + 0.5f) * 0.125f - 0.5f;
                fh = fminf(fmaxf(fh, 0.f), (float)(HIN - 1));
                int h0c = min((int)fh, HIN - 2);
                float ah = fh - (float)h0c;
                int g = gwb >> 3;
                int cm1 = max(g - 1, 0);
                int cp1 = min(g + 1, WIN - 1);
                const float* p00 = cvol + (d0c * HIN + h0c) * WIN;
                const float* p01 = p00 + WIN;
                const float* p10 = p00 + HIN * WIN;
                const float* p11 = p10 + WIN;
                float q00, q01, q10, q11, a0, a1, a2;
                q00 = p00[cm1]; q01 = p01[cm1];
                q10 = p10[cm1]; q11 = p11[cm1];
                a0 = (q00 + ah * (q01 - q00)) * (1.f - ad) +
                     (q10 + ah * (q11 - q10)) * ad;
                q00 = p00[g]; q01 = p01[g];
                q10 = p10[g]; q11 = p11[g];
                a1 = (q00 + ah * (q01 - q00)) * (1.f - ad) +
                     (q10 + ah * (q11 - q10)) * ad;
                q00 = p00[cp1]; q01 = p01[cp1];
                q10 = p10[cp1]; q11 = p11[cp1];
                a2 = (q00 + ah * (q01 - q00)) * (1.f - ad) +
                     (q10 + ah * (q11 - q10)) * ad;
                aqp[k][0] =
                    (unsigned)bf16bits(a0) | ((unsigned)bf16bits(a1) << 16);
                aqp[k][1] = (unsigned)bf16bits(a2);
            } else {
                aqp[k][0] = 0u;
                aqp[k][1] = 0u;
            }
        }
        __syncthreads(); // previous chunk's readers done
        // ---- staging phase B: compile-time-weight w-lerp, LDS scatter ----
#pragma unroll
        for (int k = 0; k < 4; ++k) {
            if (k < 3 || tid < 32) {
                int j = tid + k * 256;
                int seg = j & 3;
                int rowjob = j >> 2;
                int dl = rowjob / 20;
                int r = rowjob - dl * 20;
                int base = (r * ROWSTRIDE + seg * 8) * PIXSTRIDE + dl;
                float a0 = __uint_as_float(aqp[k][0] << 16);
                float a1 = __uint_as_float(aqp[k][0] & 0xFFFF0000u);
                float a2 = __uint_as_float(aqp[k][1] << 16);
                float d01 = a1 - a0, d12 = a2 - a1;
                su[base + 0 * PIXSTRIDE] = a0 + 0.5625f * d01;
                su[base + 1 * PIXSTRIDE] = a0 + 0.6875f * d01;
                su[base + 2 * PIXSTRIDE] = a0 + 0.8125f * d01;
                su[base + 3 * PIXSTRIDE] = a0 + 0.9375f * d01;
                su[base + 4 * PIXSTRIDE] = a1 + 0.0625f * d12;
                su[base + 5 * PIXSTRIDE] = a1 + 0.1875f * d12;
                su[base + 6 * PIXSTRIDE] = a1 + 0.3125f * d12;
                su[base + 7 * PIXSTRIDE] = a1 + 0.4375f * d12;
            }
        }
        __syncthreads();

        float acc[8] = {0.f, 0.f, 0.f, 0.f, 0.f, 0.f, 0.f, 0.f};
#pragma unroll
        for (int i = 0; i < 5; ++i) {
#pragma unroll
            for (int j = 0; j < 5; ++j) {
                const int t = i * 5 + j;
                const float* sp = su + pbase + (i * ROWSTRIDE + j) * PIXSTRIDE;
                float4 va = *(const float4*)sp;
                float4 vb = *(const float4*)(sp + 4);
                float2 vc = *(const float2*)(sp + 8);
                const float g0 = GW(t);
                const float g1 = GW(25 + t);
                const float g2 = GW(50 + t);
                acc[0] += g1 * va.x + g0 * va.y + g2 * va.z;
                acc[1] += g1 * va.y + g0 * va.z + g2 * va.w;
                acc[2] += g1 * va.z + g0 * va.w + g2 * vb.x;
                acc[3] += g1 * va.w + g0 * vb.x + g2 * vb.y;
                acc[4] += g1 * vb.x + g0 * vb.y + g2 * vb.z;
                acc[5] += g1 * vb.y + g0 * vb.z + g2 * vb.w;
                acc[6] += g1 * vb.z + g0 * vb.w + g2 * vc.x;
                acc[7] += g1 * vb.w + g0 * vc.x + g2 * vc.y;
            }
        }

        if (d0 + 8 <= dend) {
#pragma unroll
            for (int dd = 0; dd < 8; ++dd)
                ybase[(size_t)(d0 + dd) * NPIX] =
                    __float2bfloat16(acc[dd] * inv);
        } else {
#pragma unroll
            for (int dd = 0; dd < 8; ++dd)
                if (d0 + dd < dend)
                    ybase[(size_t)(d0 + dd) * NPIX] =
                        __float2bfloat16(acc[dd] * inv);
        }
    }
}

// ---------------------------------------------------------------------------
// LGA pass 2: bf16 y1 staging from HBM (round-9 measured 128-VGPR path),
// fused online softmin + per-z partials. Byte-identical to round 9.
// ---------------------------------------------------------------------------
__global__ __launch_bounds__(256) void lga2_kernel(
    const __hip_bfloat16* __restrict__ xin,
    const float* __restrict__ lg1,
    float* __restrict__ part) {
    const int tid = threadIdx.x;
    const int tx = tid & 15;
    const int ty = tid >> 4;
    const int w0p = blockIdx.x * 16;
    const int h0p = blockIdx.y * 16;
    const int zb = blockIdx.z * DSPLIT;
    const int dend = min(zb + DSPLIT, DOUT);
    const int pix = (h0p + ty) * WOUT + (w0p + tx);
    const unsigned short* xus = (const unsigned short*)xin;

    __shared__ __align__(16) float su[SUWORDS];

    float asum = 0.f;
    unsigned gp[38];
#pragma unroll
    for (int p = 0; p < 38; ++p) {
        int c0 = 2 * p, c1 = 2 * p + 1;
        float w0 = lg1[c0 * NPIX + pix];
        float w1 = (c1 < 75) ? lg1[c1 * NPIX + pix] : 0.f;
        unsigned b0 = bf16bits(w0), b1 = bf16bits(w1);
        asum += fabsf(__uint_as_float(b0 << 16)) +
                fabsf(__uint_as_float(b1 << 16));
        gp[p] = b0 | (b1 << 16);
    }
    const float inv = 1.f / fmaxf(asum, 1e-12f);

    const int pbase = (ty * ROWSTRIDE + tx + 6) * PIXSTRIDE;

    float m = -1e30f, l = 0.f, s_acc = 0.f;

    for (int d0 = zb; d0 < dend; d0 += 8) {
        uint4 dat[4];
        int lbase[4];
#pragma unroll
        for (int k = 0; k < 4; ++k) {
            const bool a = (k < 3) || (tid < 32); // NJOBS = 800
            int j = tid + k * 256;
            int seg = j & 3;
            int rowjob = j >> 2;
            int dl = rowjob / 20;
            int r = rowjob - dl * 20;
            int gh = h0p - 2 + r;
            int gwb = w0p - 8 + seg * 8;
            int gd = d0 - 1 + dl;
            lbase[k] = (r * ROWSTRIDE + seg * 8) * PIXSTRIDE + dl;
            uint4 v = make_uint4(0u, 0u, 0u, 0u);
            if (a && gd >= 0 && gd < DOUT && gh >= 0 && gh < HOUT &&
                gwb >= 0 && (gwb + 8) <= WOUT)
                v = *(const uint4*)(xus + (size_t)gd * NPIX + gh * WOUT + gwb);
            dat[k] = v;
        }
        __syncthreads();
#pragma unroll
        for (int k = 0; k < 4; ++k) {
            if (k < 3 || tid < 32) {
                int base = lbase[k];
                unsigned q;
                q = dat[k].x;
                su[base + 0 * PIXSTRIDE] = __uint_as_float(q << 16);
                su[base + 1 * PIXSTRIDE] = __uint_as_float(q & 0xFFFF0000u);
                q = dat[k].y;
                su[base + 2 * PIXSTRIDE] = __uint_as_float(q << 16);
                su[base + 3 * PIXSTRIDE] = __uint_as_float(q & 0xFFFF0000u);
                q = dat[k].z;
                su[base + 4 * PIXSTRIDE] = __uint_as_float(q << 16);
                su[base + 5 * PIXSTRIDE] = __uint_as_float(q & 0xFFFF0000u);
                q = dat[k].w;
                su[base + 6 * PIXSTRIDE] = __uint_as_float(q << 16);
                su[base + 7 * PIXSTRIDE] = __uint_as_float(q & 0xFFFF0000u);
            }
        }
        __syncthreads();

        float acc[8] = {0.f, 0.f, 0.f, 0.f, 0.f, 0.f, 0.f, 0.f};
#pragma unroll
        for (int i = 0; i < 5; ++i) {
#pragma unroll
            for (int j = 0; j < 5; ++j) {
                const int t = i * 5 + j;
                const float* sp = su + pbase + (i * ROWSTRIDE + j) * PIXSTRIDE;
                float4 va = *(const float4*)sp;
                float4 vb = *(const float4*)(sp + 4);
                float2 vc = *(const float2*)(sp + 8);
                const float g0 = GW(t);
                const float g1 = GW(25 + t);
                const float g2 = GW(50 + t);
                acc[0] += g1 * va.x + g0 * va.y + g2 * va.z;
                acc[1] += g1 * va.y + g0 * va.z + g2 * va.w;
                acc[2] += g1 * va.z + g0 * va.w + g2 * vb.x;
                acc[3] += g1 * va.w + g0 * vb.x + g2 * vb.y;
                acc[4] += g1 * vb.x + g0 * vb.y + g2 * vb.z;
                acc[5] += g1 * vb.y + g0 * vb.z + g2 * vb.w;
                acc[6] += g1 * vb.z + g0 * vb.w + g2 * vc.x;
                acc[7] += g1 * vb.w + g0 * vc.x + g2 * vc.y;
            }
        }

        if (d0 + 8 <= dend) {
            float v0 = -acc[0] * inv, v1 = -acc[1] * inv;
            float v2 = -acc[2] * inv, v3 = -acc[3] * inv;
            float v4 = -acc[4] * inv, v5 = -acc[5] * inv;
            float v6 = -acc[6] * inv, v7 = -acc[7] * inv;
            float mx = fmaxf(fmaxf(fmaxf(v0, v1), fmaxf(v2, v3)),
                             fmaxf(fmaxf(v4, v5), fmaxf(v6, v7)));
            mx = fmaxf(mx, m);
            float sc = __expf(m - mx);
            float e0 = __expf(v0 - mx), e1 = __expf(v1 - mx);
            float e2 = __expf(v2 - mx), e3 = __expf(v3 - mx);
            float e4 = __expf(v4 - mx), e5 = __expf(v5 - mx);
            float e6 = __expf(v6 - mx), e7 = __expf(v7 - mx);
            l = l * sc + ((e0 + e1) + (e2 + e3)) + ((e4 + e5) + (e6 + e7));
            float fd0 = (float)d0;
            s_acc = s_acc * sc + e0 * fd0 + e1 * (fd0 + 1.f) +
                    e2 * (fd0 + 2.f) + e3 * (fd0 + 3.f) + e4 * (fd0 + 4.f) +
                    e5 * (fd0 + 5.f) + e6 * (fd0 + 6.f) + e7 * (fd0 + 7.f);
            m = mx;
        } else {
#pragma unroll
            for (int dd = 0; dd < 8; ++dd) {
                int d = d0 + dd;
                if (d < dend) {
                    float v = -acc[dd] * inv;
                    float mx = fmaxf(m, v);
                    float sc = __expf(m - mx);
                    float e = __expf(v - mx);
                    l = l * sc + e;
                    s_acc = s_acc * sc + e * (float)d;
                    m = mx;
                }
            }
        }
    }

    float* pz = part + (size_t)blockIdx.z * 3 * NPIX;
    pz[pix] = m;
    pz[NPIX + pix] = l;
    pz[2 * NPIX + pix] = s_acc;
}
#undef GW

// ---------------------------------------------------------------------------
// Kernel 4: merge NZ online-softmin partials per pixel -> disparity.
// ---------------------------------------------------------------------------
__global__ void reduce2_kernel(const float* __restrict__ part,
                               float* __restrict__ out) {
    int pix = blockIdx.x * blockDim.x + threadIdx.x;
    float M = -1e30f, L = 0.f, S = 0.f;
#pragma unroll
    for (int z = 0; z < NZ; ++z) {
        const float* pz = part + (size_t)z * 3 * NPIX;
        float m = pz[pix];
        float l = pz[NPIX + pix];
        float s = pz[2 * NPIX + pix];
        float mx = fmaxf(M, m);
        float a = __expf(M - mx);
        float b = __expf(m - mx);
        L = L * a + l * b;
        S = S * a + s * b;
        M = mx;
    }
    out[pix] = S / L;
}

// ---------------------------------------------------------------------------
extern "C" void kernel_launch(void* const* d_in, const int* in_sizes, int n_in,
                              void* d_out, int out_size, void* d_ws,
                              size_t ws_size, hipStream_t stream) {
    const float* x = (const float*)d_in[0];
    const float* lg1 = (const float*)d_in[1];
    const float* cw = (const float*)d_in[2];
    float* out = (float*)d_out;

    // ws: c fp32 [100352] | region A bf16 [NUPS] | region B bf16 [NUPS].
    // conv partials [8][NCONV] overlay region B; lga1 writes y1 to region B;
    // lga2 writes (m,l,s) partials to region A.
    float* c = (float*)d_ws;
    __hip_bfloat16* regA = (__hip_bfloat16*)((char*)d_ws + (size_t)NCONV * 4);
    __hip_bfloat16* y1 = regA + (size_t)NUPS;
    float* cpart = (float*)y1;
    float* part = (float*)regA;

    dim3 cgrid(NCONV / 256, CGRP);
    conv3d_kernel<<<cgrid, 256, 0, stream>>>(x, cw, cpart);
    convfold_kernel<<<NCONV / 256, 256, 0, stream>>>(cpart, c);

    dim3 grid(WOUT / 16, HOUT / 16, NZ); // 32 x 16 x 4 = 2048 blocks
    lga1_kernel<<<grid, 256, 0, stream>>>(c, lg1, y1);
    lga2_kernel<<<grid, 256, 0, stream>>>(y1, lg1, part);

    reduce2_kernel<<<NPIX / 256, 256, 0, stream>>>(part, out);
}